// Round 6
// baseline (64.026 us; speedup 1.0000x reference)
//
#include <hip/hip_runtime.h>

typedef unsigned short ushort_t;
typedef __attribute__((ext_vector_type(8))) __bf16 bf16x8;
typedef __attribute__((ext_vector_type(8))) short short8_t;
typedef __attribute__((ext_vector_type(4))) float f32x4;

#define C127 (127.0f / 128.0f)

__device__ inline ushort_t f2bf(float f) {
  unsigned u = __builtin_bit_cast(unsigned, f);
  u += 0x7fffu + ((u >> 16) & 1u);
  return (ushort_t)(u >> 16);
}

__device__ inline bf16x8 ldfrag(const ushort_t* p) {
  return __builtin_bit_cast(bf16x8, *(const short8_t*)p);
}

__device__ inline f32x4 mfma16(bf16x8 a, bf16x8 b, f32x4 c) {
  return __builtin_amdgcn_mfma_f32_16x16x32_bf16(a, b, c, 0, 0, 0);
}

// (row,col) -> position in a 64-wide swizzled tile
__device__ inline int swz(int row, int col) {
  return row * 64 + (col ^ ((row & 7) << 3));
}

__device__ inline void gl_lds16(const ushort_t* g, ushort_t* l) {
  __builtin_amdgcn_global_load_lds(
      (const __attribute__((address_space(1))) unsigned*)(g),
      (__attribute__((address_space(3))) unsigned*)(l),
      16, 0, 0);
}

// ================= prep (all 16B/thread) =================
// wftf: fragment-major per s: [ct=wcol/16 (128)][kc=k/32 (nkc)] tiles of 512
//       elems; within tile: lane&15=wcol, (lane>>4)*8+e = k.  s offsets (elems):
//       0 / 262144 / 786432 / 1572864
// xbt64: [rb 64][kc 12][64x64 swz tile 4096 elems]
// bfm:   [nb 8][kc 14][32x64 swz 2048]
// w1b:   row-major [4][16][1024]
__global__ __launch_bounds__(256) void k_prep(
    const float* __restrict__ x,
    const float* Wp, const float* Wmi, const float* Wma, const float* Wd,
    const float* W1p, const float* W1mi, const float* W1ma, const float* W1d,
    const float* Wop, const float* Womi, const float* Woma, const float* Wod,
    const float* bop, const float* bomi, const float* boma, const float* bod,
    const float* Wc,
    ushort_t* wftf, ushort_t* xbt, ushort_t* bfm, ushort_t* w1b, float* biassum)
{
  int i = blockIdx.x * 256 + threadIdx.x;
  const int RW = 294912, RX = RW + 393216, RB = RX + 28672, R1 = RB + 8192,
            RE = R1 + 32;
  if (i < RW) {
    const float* src; int nkc, d, jj;
    if (i < 32768)       { src = Wp;  nkc = 4;  d = 128; jj = i; }
    else if (i < 98304)  { src = Wmi; nkc = 8;  d = 256; jj = i - 32768; }
    else if (i < 196608) { src = Wma; nkc = 12; d = 384; jj = i - 98304; }
    else                 { src = Wd;  nkc = 12; d = 384; jj = i - 196608; }
    int tile = jj >> 6, lane = jj & 63;
    int ct = tile / nkc, kc = tile - ct * nkc;
    int wcol = ct * 16 + (lane & 15);
    int k = kc * 32 + (lane >> 4) * 8;
    const float* sp = src + (size_t)wcol * d + k;
    ushort_t tmp[8];
#pragma unroll
    for (int e = 0; e < 8; ++e) tmp[e] = f2bf(sp[e]);
    *(short8_t*)(wftf + (size_t)i * 8) = *(const short8_t*)tmp;
  } else if (i < RX) {
    int i2 = i - RW;
    int tile = i2 >> 9, u = i2 & 511;
    int trow = u >> 3, scol0 = (u & 7) * 8;
    int rb = tile / 12, kc = tile - rb * 12;
    int col0 = scol0 ^ ((trow & 7) << 3);
    const float* sp = x + (size_t)(rb * 64 + trow) * 768 + kc * 64 + col0;
    ushort_t tmp[8];
#pragma unroll
    for (int e = 0; e < 8; ++e) tmp[e] = f2bf(sp[e]);
    *(short8_t*)(xbt + (size_t)i2 * 8) = *(const short8_t*)tmp;
  } else if (i < RB) {
    int i3 = i - RX;
    int tile = i3 >> 8, trow = (i3 & 255) >> 3, scol0 = (i3 & 7) * 8;
    int nb = tile / 14, kblk = tile - nb * 14;
    int col0 = scol0 ^ ((trow & 7) << 3);
    int n = nb * 32 + trow, c0 = kblk * 64 + col0;
    const float* sp;
    if (c0 < 128) {
      int ss = c0 >> 5, jj = c0 & 31;
      const float* src = (ss == 0) ? Wop : (ss == 1) ? Womi : (ss == 2) ? Woma : Wod;
      sp = src + n * 32 + jj;
    } else {
      sp = Wc + n * 768 + (c0 - 128);
    }
    ushort_t tmp[8];
#pragma unroll
    for (int e = 0; e < 8; ++e) tmp[e] = f2bf(sp[e]);
    *(short8_t*)(bfm + (size_t)i3 * 8) = *(const short8_t*)tmp;
  } else if (i < R1) {
    int i4 = i - RB;
    int s = i4 >> 11, r = i4 & 2047;
    const float* src = (s == 0) ? W1p : (s == 1) ? W1mi : (s == 2) ? W1ma : W1d;
    ushort_t tmp[8];
#pragma unroll
    for (int e = 0; e < 8; ++e) tmp[e] = f2bf(src[r * 8 + e]);
    *(short8_t*)(w1b + (size_t)i4 * 8) = *(const short8_t*)tmp;
  } else if (i < RE) {
    int i5 = i - R1;
#pragma unroll
    for (int e = 0; e < 8; ++e) {
      int n = i5 * 8 + e;
      biassum[n] = bop[n] + bomi[n] + boma[n] + bod[n];
    }
  }
}

// ====== ft GEMM: A resident in LDS, B streamed to regs, W1 fused ======
struct FtP {
  const ushort_t* xbt;    // 64-row tiles
  const ushort_t* wftf;   // fragment-major weights
  const ushort_t* w1b;
  float* pf;              // [2 gh][4 s][4096][16]
  const float* bft0; const float* bft1; const float* bft2; const float* bft3;
};

__global__ __launch_bounds__(256, 2) void k_ft(FtP p) {
  int b = blockIdx.x;
  int idx = b >> 1;
  // interleave long (s2/s3) and short (s1/s0) blocks for CU balance
  int s = (b & 1) ? ((idx & 1) ? 0 : 1) : (2 + (idx & 1));
  int rem = idx >> 1;
  int chunk = rem >> 1, gh = rem & 1;

  int nkc, soff; const float* bft; unsigned long long ctbl;
  if (s == 0)      { nkc = 4;  soff = 0;       bft = p.bft0; ctbl = 0x60ULL; }
  else if (s == 1) { nkc = 8;  soff = 262144;  bft = p.bft1; ctbl = 0x8721ULL; }
  else if (s == 2) { nkc = 12; soff = 786432;  bft = p.bft2; ctbl = 0xBA9543ULL; }
  else             { nkc = 12; soff = 1572864; bft = p.bft3; ctbl = 0xBA8542ULL; }
  int nkb = nkc >> 1;   // number of 64-k A tiles

  int tid = threadIdx.x, lane = tid & 63, wid = tid >> 6;   // wid = col group
  int lr = lane & 15, lk8 = (lane >> 4) * 8, lrow = (lane >> 4) * 4;

  __shared__ ushort_t lA[6 * 4096];     // A resident: up to 64 x 384
  __shared__ ushort_t act[64 * 128];    // activation exchange (128-wide swz)

  // ---- stage A once ----
  for (int t = 0; t < nkb; ++t) {
    int ch = (int)((ctbl >> (4 * t)) & 15ULL);
    const ushort_t* at = p.xbt + ((size_t)chunk * 12 + ch) * 4096;
#pragma unroll
    for (int c = 0; c < 2; ++c) {
      int off = (c * 4 + wid) * 512;
      gl_lds16(at + off + lane * 8, &lA[t * 4096 + off]);
    }
  }
  __syncthreads();

  f32x4 facc = {0.f, 0.f, 0.f, 0.f};

#define LOADB(X, kc_)                                                   \
  {                                                                     \
    int kc__ = (kc_);                                                   \
    X##00 = ldfrag(Bp00 + (size_t)kc__ * 512);                          \
    X##01 = ldfrag(Bp01 + (size_t)kc__ * 512);                          \
    X##10 = ldfrag(Bp10 + (size_t)kc__ * 512);                          \
    X##11 = ldfrag(Bp11 + (size_t)kc__ * 512);                          \
  }
#define AREAD(gr_)                                                      \
  {                                                                     \
    int gr__ = (gr_);                                                   \
    int kb__ = (gr__ >> 1) * 4096, kc__ = (gr__ & 1) * 32 + lk8;        \
    _Pragma("unroll") for (int m = 0; m < 4; ++m)                       \
        aa[m] = ldfrag(&lA[kb__ + swz(m * 16 + lr, kc__)]);             \
  }
#define MFMAS(X)                                                        \
  {                                                                     \
    _Pragma("unroll") for (int m = 0; m < 4; ++m) {                     \
      acc[0][m][0] = mfma16(aa[m], X##00, acc[0][m][0]);                \
      acc[0][m][1] = mfma16(aa[m], X##01, acc[0][m][1]);                \
      acc[1][m][0] = mfma16(aa[m], X##10, acc[1][m][0]);                \
      acc[1][m][1] = mfma16(aa[m], X##11, acc[1][m][1]);                \
    }                                                                   \
  }

  for (int gp = 0; gp < 4; ++gp) {
    int g0 = gh * 8 + gp * 2;
    int ct0 = g0 * 4 + wid * 2;
    const ushort_t* Bp00 = p.wftf + soff + (size_t)(ct0 * nkc) * 512 + lane * 8;
    const ushort_t* Bp01 = p.wftf + soff + (size_t)((ct0 + 1) * nkc) * 512 + lane * 8;
    const ushort_t* Bp10 = p.wftf + soff + (size_t)((ct0 + 64) * nkc) * 512 + lane * 8;
    const ushort_t* Bp11 = p.wftf + soff + (size_t)((ct0 + 65) * nkc) * 512 + lane * 8;

    f32x4 acc[2][4][2];
#pragma unroll
    for (int h = 0; h < 2; ++h)
#pragma unroll
      for (int m = 0; m < 4; ++m)
#pragma unroll
        for (int n = 0; n < 2; ++n) acc[h][m][n] = (f32x4){0.f, 0.f, 0.f, 0.f};

    bf16x8 bA00, bA01, bA10, bA11, bB00, bB01, bB10, bB11, aa[4];

    LOADB(bA, 0);
    for (int t = 0; t < nkb; ++t) {
      LOADB(bB, 2 * t + 1);
      AREAD(2 * t);
      MFMAS(bA);
      int g2 = 2 * t + 2; if (g2 >= nkc) g2 = nkc - 1;
      LOADB(bA, g2);
      AREAD(2 * t + 1);
      MFMAS(bB);
    }

    __syncthreads();   // close previous gp's W1 act reads
    // activation -> act LDS (128-wide swizzled)
#pragma unroll
    for (int m = 0; m < 4; ++m)
#pragma unroll
      for (int n = 0; n < 2; ++n) {
        int col = wid * 32 + n * 16 + lr;        // 0..127 within g-pair
        float bb1 = bft[g0 * 64 + col];
        float bb2 = bft[1024 + g0 * 64 + col];
#pragma unroll
        for (int r = 0; r < 4; ++r) {
          int row = m * 16 + lrow + r;
          float v = (acc[0][m][n][r] + bb1) * (acc[1][m][n][r] + bb2) * C127;
          act[row * 128 + (col ^ ((row & 7) << 3))] = f2bf(v);
        }
      }
    __syncthreads();

    // W1 partial: rows wid*16..+16, k = 128 cols of this g-pair
#pragma unroll
    for (int kk = 0; kk < 4; ++kk) {
      int row = wid * 16 + lr;
      int col = kk * 32 + lk8;
      bf16x8 af = ldfrag(&act[row * 128 + (col ^ ((row & 7) << 3))]);
      bf16x8 bw = ldfrag(p.w1b + s * 16384 + lr * 1024 + g0 * 64 + col);
      facc = mfma16(af, bw, facc);
    }
  }
#undef LOADB
#undef AREAD
#undef MFMAS

  float* pfp = p.pf +
      ((size_t)((gh * 4 + s) * 4096 + chunk * 64 + wid * 16 + lrow)) * 16 + lr;
#pragma unroll
  for (int r = 0; r < 4; ++r) pfp[r * 16] = facc[r];
}

// ================= reduce 2 partials -> cat (64-row tiles) =================
__global__ __launch_bounds__(256) void k_fin(
    const float* __restrict__ pf, ushort_t* __restrict__ cat_t,
    const float* b1p, const float* b1mi, const float* b1ma, const float* b1d)
{
  int tid = threadIdx.x;
  int j = tid & 15, s = (tid >> 4) & 3, rl = tid >> 6;
  int row = blockIdx.x * 4 + rl;
  const float* b1 = (s == 0) ? b1p : (s == 1) ? b1mi : (s == 2) ? b1ma : b1d;
  float acc = pf[(size_t)s * 65536 + row * 16 + j] +
              pf[(size_t)(4 + s) * 65536 + row * 16 + j];
  float f = acc + b1[j];
  float cf = fminf(fmaxf(f, 0.f), 1.f);
  float cs = fminf(f * f * C127, 1.f);
  int rb = row >> 6, trow = row & 63;
  int c1 = s * 32 + j;
  {
    int kc = c1 >> 6, tc = c1 & 63;
    cat_t[(size_t)(rb * 2 + kc) * 4096 + trow * 64 + (tc ^ ((trow & 7) << 3))] =
        f2bf(cf);
  }
  {
    int c2 = c1 + 16;
    int kc = c2 >> 6, tc = c2 & 63;
    cat_t[(size_t)(rb * 2 + kc) * 4096 + trow * 64 + (tc ^ ((trow & 7) << 3))] =
        f2bf(cs);
  }
}

// ============ final GEMM: 64-row blocks, dbuf stage-ahead ============
__global__ __launch_bounds__(256) void k_out(
    const ushort_t* __restrict__ cat_t, const ushort_t* __restrict__ xbt,
    const ushort_t* __restrict__ bfm, const float* __restrict__ biassum,
    float* __restrict__ out)
{
  int rowblk = blockIdx.y;   // 0..63 (64 rows each)
  int nb = blockIdx.x;       // 0..7  (32 cols each)
  int tid = threadIdx.x, lane = tid & 63, wid = tid >> 6;
  int lr = lane & 15, lk = (lane >> 4) * 8, lrow = (lane >> 4) * 4;

  __shared__ ushort_t lA[2][4096];
  __shared__ ushort_t lB[2][2048];

  f32x4 acc[2];
  acc[0] = (f32x4){0.f, 0.f, 0.f, 0.f};
  acc[1] = (f32x4){0.f, 0.f, 0.f, 0.f};

#define STGO(bufi, kb_)                                                       \
  {                                                                           \
    int kb__ = (kb_);                                                         \
    const ushort_t* at = (kb__ < 2)                                           \
        ? cat_t + ((size_t)rowblk * 2 + kb__) * 4096                          \
        : xbt + ((size_t)rowblk * 12 + (kb__ - 2)) * 4096;                    \
    const ushort_t* bt = bfm + ((size_t)nb * 14 + kb__) * 2048;               \
    _Pragma("unroll") for (int c = 0; c < 2; ++c) {                           \
      int off = (c * 4 + wid) * 512;                                          \
      gl_lds16(at + off + lane * 8, &lA[bufi][off]);                          \
    }                                                                         \
    { int off = wid * 512; gl_lds16(bt + off + lane * 8, &lB[bufi][off]); }   \
  }

  STGO(0, 0);
  __syncthreads();
  for (int kb = 0; kb < 14; ++kb) {
    int cur = kb & 1;
    if (kb + 1 < 14) STGO((kb + 1) & 1, kb + 1);
#pragma unroll
    for (int kk = 0; kk < 64; kk += 32) {
      bf16x8 b0 = ldfrag(&lB[cur][swz(lr, kk + lk)]);
      bf16x8 b1v = ldfrag(&lB[cur][swz(16 + lr, kk + lk)]);
      bf16x8 a = ldfrag(&lA[cur][swz(wid * 16 + lr, kk + lk)]);
      acc[0] = mfma16(a, b0, acc[0]);
      acc[1] = mfma16(a, b1v, acc[1]);
    }
    __syncthreads();
  }
#undef STGO

#pragma unroll
  for (int n = 0; n < 2; ++n) {
    int col = nb * 32 + n * 16 + lr;
    float bs = biassum[col];
#pragma unroll
    for (int r = 0; r < 4; ++r) {
      int row = rowblk * 64 + wid * 16 + lrow + r;
      out[(size_t)row * 256 + col] = acc[n][r] + bs;
    }
  }
}

extern "C" void kernel_launch(void* const* d_in, const int* in_sizes, int n_in,
                              void* d_out, int out_size, void* d_ws, size_t ws_size,
                              hipStream_t stream)
{
  const float* x     = (const float*)d_in[0];
  const float* pWft  = (const float*)d_in[5];   const float* pbft  = (const float*)d_in[6];
  const float* pW1   = (const float*)d_in[7];   const float* pb1   = (const float*)d_in[8];
  const float* pWo   = (const float*)d_in[9];   const float* pbo   = (const float*)d_in[10];
  const float* miWft = (const float*)d_in[11];  const float* mibft = (const float*)d_in[12];
  const float* miW1  = (const float*)d_in[13];  const float* mib1  = (const float*)d_in[14];
  const float* miWo  = (const float*)d_in[15];  const float* mibo  = (const float*)d_in[16];
  const float* maWft = (const float*)d_in[17];  const float* mabft = (const float*)d_in[18];
  const float* maW1  = (const float*)d_in[19];  const float* mab1  = (const float*)d_in[20];
  const float* maWo  = (const float*)d_in[21];  const float* mabo  = (const float*)d_in[22];
  const float* dWft  = (const float*)d_in[23];  const float* dbft  = (const float*)d_in[24];
  const float* dW1   = (const float*)d_in[25];  const float* db1   = (const float*)d_in[26];
  const float* dWo   = (const float*)d_in[27];  const float* dbo   = (const float*)d_in[28];
  const float* Wc    = (const float*)d_in[29];

  char* wsb = (char*)d_ws;
  ushort_t* xbt     = (ushort_t*)(wsb + 0);          //  6,291,456
  ushort_t* wftf    = (ushort_t*)(wsb + 6291456);    //  4,718,592
  ushort_t* w1b     = (ushort_t*)(wsb + 11010048);   //    131,072
  ushort_t* bfm     = (ushort_t*)(wsb + 11141120);   //    458,752
  float*    biassum = (float*)(wsb + 11599872);      //      1,024
  float*    pf      = (float*)(wsb + 11600896);      //  2,097,152
  ushort_t* cat_t   = (ushort_t*)(wsb + 13698048);   //  1,048,576

  k_prep<<<dim3(2833), dim3(256), 0, stream>>>(
      x, pWft, miWft, maWft, dWft, pW1, miW1, maW1, dW1,
      pWo, miWo, maWo, dWo, pbo, mibo, mabo, dbo, Wc,
      wftf, xbt, bfm, w1b, biassum);

  FtP fp;
  fp.xbt = xbt; fp.wftf = wftf; fp.w1b = w1b; fp.pf = pf;
  fp.bft0 = pbft; fp.bft1 = mibft; fp.bft2 = mabft; fp.bft3 = dbft;
  k_ft<<<dim3(512), dim3(256), 0, stream>>>(fp);

  k_fin<<<dim3(1024), dim3(256), 0, stream>>>(pf, cat_t, pb1, mib1, mab1, db1);

  k_out<<<dim3(8, 64), dim3(256), 0, stream>>>(cat_t, xbt, bfm, biassum, (float*)d_out);
}